// Round 8
// baseline (247.829 us; speedup 1.0000x reference)
//
#include <hip/hip_runtime.h>

// SparseActivation: per row of D=2048 fp32, keep top K=204 by |x|, scale D/K.
// TWO-KERNEL SPLIT (rounds 2-7 proved the fused wave-per-row structure is
// MLP-pinned at ~2.5 TB/s / ~88us regardless of VALU work):
//   A) threshold: one wave per row, register bisection (seeded, early-exit),
//      writes 4 BYTES per row (exact threshold bits) to d_ws. No row stores.
//      Rare boundary-tie rows resolved entirely in A (writes that row's
//      output, posts SKIP sentinel so B leaves it alone).
//   B) apply: pure streaming grid-stride, 4 independent float4/thread,
//      out = (|x| >= T[row]) ? x*scale : 0. T array (64 KB) stays in L1/L2;
//      input is L3-resident after A's pass.

constexpr int D_DIM = 2048;
constexpr int K_SEL = 204;         // int(2048 * 0.1)
constexpr int EPL   = 32;          // elements per lane per row (wave64)
constexpr unsigned SKIP = 0xFFFFFFFFu;  // sentinel: row already written by A

// Full-wave64 integer sum via DPP; returns total (scalar, from lane 63).
__device__ __forceinline__ int dpp_reduce_add(int x) {
    x += __builtin_amdgcn_update_dpp(0, x, 0x111, 0xF, 0xF, true);  // row_shr:1
    x += __builtin_amdgcn_update_dpp(0, x, 0x112, 0xF, 0xF, true);  // row_shr:2
    x += __builtin_amdgcn_update_dpp(0, x, 0x114, 0xF, 0xF, true);  // row_shr:4
    x += __builtin_amdgcn_update_dpp(0, x, 0x118, 0xF, 0xF, true);  // row_shr:8
    x += __builtin_amdgcn_update_dpp(0, x, 0x142, 0xA, 0xF, false); // row_bcast:15
    x += __builtin_amdgcn_update_dpp(0, x, 0x143, 0xC, 0xF, false); // row_bcast:31
    return __builtin_amdgcn_readlane(x, 63);
}

__device__ __forceinline__ int count_ge(const unsigned (&a)[EPL], unsigned t) {
    int c0 = 0, c1 = 0, c2 = 0, c3 = 0;
#pragma unroll
    for (int j = 0; j < EPL; j += 4) {
        c0 += (a[j + 0] >= t) ? 1 : 0;
        c1 += (a[j + 1] >= t) ? 1 : 0;
        c2 += (a[j + 2] >= t) ? 1 : 0;
        c3 += (a[j + 3] >= t) ? 1 : 0;
    }
    return dpp_reduce_add((c0 + c1) + (c2 + c3));
}

// ---------------- Kernel A: per-row exact threshold ----------------
__global__ __launch_bounds__(256) void thresh_kernel(const float* __restrict__ x,
                                                     float* __restrict__ out,
                                                     unsigned* __restrict__ tbits) {
    const int wave = threadIdx.x >> 6;
    const int lane = threadIdx.x & 63;
    const long long row = (long long)blockIdx.x * 4 + wave;
    const float* xr = x + row * D_DIM;

    // Element (b, lane, e): row index = 256*b + 4*lane + e, j = 4*b + e.
    unsigned a[EPL];
    unsigned signs = 0u;   // only consumed on the rare tie path
    const float4* xp = reinterpret_cast<const float4*>(xr);
#pragma unroll
    for (int b = 0; b < 8; ++b) {
        const float4 f = xp[b * 64 + lane];
        const unsigned w0 = __float_as_uint(f.x), w1 = __float_as_uint(f.y);
        const unsigned w2 = __float_as_uint(f.z), w3 = __float_as_uint(f.w);
        a[4 * b + 0] = w0 & 0x7fffffffu; signs |= (w0 >> 31) << (4 * b + 0);
        a[4 * b + 1] = w1 & 0x7fffffffu; signs |= (w1 >> 31) << (4 * b + 1);
        a[4 * b + 2] = w2 & 0x7fffffffu; signs |= (w2 >> 31) << (4 * b + 2);
        a[4 * b + 3] = w3 & 0x7fffffffu; signs |= (w3 >> 31) << (4 * b + 3);
    }

    // Seeded integer bisection on [lo, hi): invariant cnt_ge(lo) >= K,
    // cnt_ge(hi) < K. Early exit when cnt == K (keep-set is exactly top-K).
    unsigned lo = 0u, hi = 0x7F800000u;
    int step = 0, lastcnt = 0;
#pragma unroll 1
    while (hi - lo > 1u) {
        unsigned mid;
        if (step == 0)      mid = 0x3FD28F5Cu;                       // ~1.645
        else if (step == 1) mid = (lastcnt > K_SEL) ? 0x3FE66666u    // 1.8
                                                    : 0x3FC00000u;   // 1.5
        else                mid = lo + ((hi - lo) >> 1);
        if (mid <= lo || mid >= hi) mid = lo + ((hi - lo) >> 1);     // guard
        ++step;
        const int cnt = count_ge(a, mid);
        lastcnt = cnt;
        if (cnt == K_SEL) {
            if (lane == 0) tbits[row] = mid;   // exact: keep a >= mid
            return;
        }
        if (cnt > K_SEL) lo = mid; else hi = mid;
    }

    // lo is the exact K-th largest pattern; check boundary multiplicity.
    int ge_pack = 0;
#pragma unroll
    for (int j = 0; j < EPL; ++j) {
        ge_pack += (a[j] > lo) ? 1 : 0;
        ge_pack += (a[j] == lo) ? (1 << 16) : 0;
    }
    const int tot = dpp_reduce_add(ge_pack);
    const int cnt_gt = tot & 0xFFFF;
    const int neq = tot >> 16;
    const int r = K_SEL - cnt_gt;          // equals to keep (1 <= r <= neq)

    if (neq == r) {
        if (lane == 0) tbits[row] = lo;    // keep a >= lo is exactly top-K
        return;
    }

    // Astronomically rare: tie spans the K-boundary. Resolve here (keep the
    // r equal elements with lowest global index, matching lax.top_k) and
    // write this row's output directly; tell B to skip the row.
    const float scale = 2048.0f / 204.0f;
    float4* op = reinterpret_cast<float4*>(out + row * D_DIM);
    const unsigned long long lt = (lane == 0) ? 0ull : (~0ull >> (64 - lane));
    int base = 0;
    for (int b = 0; b < 8; ++b) {
        unsigned long long m[4];
#pragma unroll
        for (int e = 0; e < 4; ++e) m[e] = __ballot(a[4 * b + e] == lo);
        int cm = 0;
#pragma unroll
        for (int e = 0; e < 4; ++e) cm += __popcll(m[e] & lt);
        int partial = 0;
        float v[4];
#pragma unroll
        for (int e = 0; e < 4; ++e) {
            const int j = 4 * b + e;
            const int rank = base + cm + partial;
            const bool sel = (a[j] > lo) || ((a[j] == lo) && rank < r);
            const float val =
                __uint_as_float(a[j] | (((signs >> j) & 1u) << 31)) * scale;
            v[e] = sel ? val : 0.0f;
            partial += (int)((m[e] >> lane) & 1ull);
        }
        op[b * 64 + lane] = make_float4(v[0], v[1], v[2], v[3]);
#pragma unroll
        for (int e = 0; e < 4; ++e) base += __popcll(m[e]);
    }
    if (lane == 0) tbits[row] = SKIP;
}

// ---------------- Kernel B: streaming apply ----------------
// Exactly 4 float4 chunks per thread, grid-stride spacing, all 4 loads
// issued independently (memcpy-shaped MLP).
__global__ __launch_bounds__(256) void apply_kernel(const float* __restrict__ x,
                                                    const unsigned* __restrict__ tbits,
                                                    float* __restrict__ out) {
    const float scale = 2048.0f / 204.0f;
    const int stride = gridDim.x * blockDim.x;          // in float4 units
    const int i0 = blockIdx.x * blockDim.x + threadIdx.x;
    const float4* xp = reinterpret_cast<const float4*>(x);
    float4* op = reinterpret_cast<float4*>(out);

    int idx[4];
    float4 f[4];
    unsigned tb[4];
#pragma unroll
    for (int q = 0; q < 4; ++q) idx[q] = i0 + q * stride;
#pragma unroll
    for (int q = 0; q < 4; ++q) f[q] = xp[idx[q]];
#pragma unroll
    for (int q = 0; q < 4; ++q) tb[q] = tbits[idx[q] >> 9];  // 512 float4/row

#pragma unroll
    for (int q = 0; q < 4; ++q) {
        if (tb[q] == SKIP) continue;   // row already written by kernel A
        float4 g;
        g.x = ((__float_as_uint(f[q].x) & 0x7fffffffu) >= tb[q]) ? f[q].x * scale : 0.0f;
        g.y = ((__float_as_uint(f[q].y) & 0x7fffffffu) >= tb[q]) ? f[q].y * scale : 0.0f;
        g.z = ((__float_as_uint(f[q].z) & 0x7fffffffu) >= tb[q]) ? f[q].z * scale : 0.0f;
        g.w = ((__float_as_uint(f[q].w) & 0x7fffffffu) >= tb[q]) ? f[q].w * scale : 0.0f;
        op[idx[q]] = g;
    }
}

extern "C" void kernel_launch(void* const* d_in, const int* in_sizes, int n_in,
                              void* d_out, int out_size, void* d_ws, size_t ws_size,
                              hipStream_t stream) {
    const float* x = (const float*)d_in[0];
    float* out = (float*)d_out;
    unsigned* tbits = (unsigned*)d_ws;              // 16384 * 4 B = 64 KB
    const int rows = in_sizes[0] / D_DIM;           // 16384

    thresh_kernel<<<rows / 4, 256, 0, stream>>>(x, out, tbits);

    const int n4 = in_sizes[0] / 4;                 // 8,388,608 float4 chunks
    const int blocks = n4 / (256 * 4);              // 8192 -> exactly 4/thread
    apply_kernel<<<blocks, 256, 0, stream>>>(x, tbits, out);
}

// Round 9
// 238.565 us; speedup vs baseline: 1.0388x; 1.0388x over previous
//
#include <hip/hip_runtime.h>

// SparseActivation: per row of D=2048 fp32, keep top K=204 by |x|, scale D/K.
// FUSED (read-once/write-once; r8 split's extra x re-read lost ~12us).
// Structure vs r5/r7: ONE WAVE PER BLOCK (64 threads) so the 16384 row-waves
// dispatch/retire independently and stay time-staggered -- breaks the
// lockstep load-burst/compute-window synchronization that pinned 256-thread
// variants at ~2.5 TB/s (harness fill proves 6.7 TB/s is reachable).
// Each block handles 2 rows with register prefetch of row r+1 during row r's
// search. Epilogue uses NONTEMPORAL stores so the output stream doesn't
// evict the L3-resident input. Exact seeded bisection + early exit
// (cnt==K => keep-set is exactly top-K); exact lowest-index tie fallback.

constexpr int D_DIM = 2048;
constexpr int K_SEL = 204;     // int(2048 * 0.1)
constexpr int NT    = 64;      // ONE wave per block
constexpr int EPL   = 32;      // elements per lane per row
constexpr int RPW   = 2;       // rows per block

typedef float v4f __attribute__((ext_vector_type(4)));

// Full-wave64 integer sum via DPP; returns total (scalar, from lane 63).
__device__ __forceinline__ int dpp_reduce_add(int x) {
    x += __builtin_amdgcn_update_dpp(0, x, 0x111, 0xF, 0xF, true);  // row_shr:1
    x += __builtin_amdgcn_update_dpp(0, x, 0x112, 0xF, 0xF, true);  // row_shr:2
    x += __builtin_amdgcn_update_dpp(0, x, 0x114, 0xF, 0xF, true);  // row_shr:4
    x += __builtin_amdgcn_update_dpp(0, x, 0x118, 0xF, 0xF, true);  // row_shr:8
    x += __builtin_amdgcn_update_dpp(0, x, 0x142, 0xA, 0xF, false); // row_bcast:15
    x += __builtin_amdgcn_update_dpp(0, x, 0x143, 0xC, 0xF, false); // row_bcast:31
    return __builtin_amdgcn_readlane(x, 63);
}

__device__ __forceinline__ int count_ge(const unsigned (&a)[EPL], unsigned t) {
    int c0 = 0, c1 = 0, c2 = 0, c3 = 0;
#pragma unroll
    for (int j = 0; j < EPL; j += 4) {
        c0 += (a[j + 0] >= t) ? 1 : 0;
        c1 += (a[j + 1] >= t) ? 1 : 0;
        c2 += (a[j + 2] >= t) ? 1 : 0;
        c3 += (a[j + 3] >= t) ? 1 : 0;
    }
    return dpp_reduce_add((c0 + c1) + (c2 + c3));
}

// Apply threshold + store one row. exact => thr keep-set has exactly K elems;
// otherwise T is the exact K-th largest and boundary ties are ranked exactly.
__device__ __forceinline__ void finish_row(const unsigned (&a)[EPL], unsigned signs,
                                           bool exact, unsigned thr, unsigned T,
                                           float* __restrict__ outr, int lane) {
    const float scale = 2048.0f / 204.0f;
    v4f* op = reinterpret_cast<v4f*>(outr);

    if (!exact) {
        // Boundary bookkeeping (gt in low 16 bits, eq in high 16 bits).
        int ge_pack = 0;
#pragma unroll
        for (int j = 0; j < EPL; ++j) {
            ge_pack += (a[j] > T) ? 1 : 0;
            ge_pack += (a[j] == T) ? (1 << 16) : 0;
        }
        const int tot = dpp_reduce_add(ge_pack);
        const int cnt_gt = tot & 0xFFFF;
        const int neq = tot >> 16;
        const int r = K_SEL - cnt_gt;   // equals to keep

        if (neq != r) {
            // Rare: among ==T keep the r with lowest global index.
            const unsigned long long lt =
                (lane == 0) ? 0ull : (~0ull >> (64 - lane));
            int base = 0;
            for (int b = 0; b < 8; ++b) {
                unsigned long long m[4];
#pragma unroll
                for (int e = 0; e < 4; ++e) m[e] = __ballot(a[4 * b + e] == T);
                int cm = 0;
#pragma unroll
                for (int e = 0; e < 4; ++e) cm += __popcll(m[e] & lt);
                int partial = 0;
                v4f v;
#pragma unroll
                for (int e = 0; e < 4; ++e) {
                    const int j = 4 * b + e;
                    const int rank = base + cm + partial;
                    const bool sel = (a[j] > T) || ((a[j] == T) && rank < r);
                    const float val =
                        __uint_as_float(a[j] | (((signs >> j) & 1u) << 31)) * scale;
                    v[e] = sel ? val : 0.0f;
                    partial += (int)((m[e] >> lane) & 1ull);
                }
                op[b * 64 + lane] = v;
#pragma unroll
                for (int e = 0; e < 4; ++e) base += __popcll(m[e]);
            }
            return;
        }
        thr = T;  // neq == r: keep everything >= T, no tie handling needed
    }

    // Common path: keep everything >= thr; nontemporal 16B stores.
#pragma unroll
    for (int b = 0; b < 8; ++b) {
        v4f v;
#pragma unroll
        for (int e = 0; e < 4; ++e) {
            const int j = 4 * b + e;
            const float val =
                __uint_as_float(a[j] | (((signs >> j) & 1u) << 31)) * scale;
            v[e] = (a[j] >= thr) ? val : 0.0f;
        }
        __builtin_nontemporal_store(v, &op[b * 64 + lane]);
    }
}

__global__ __launch_bounds__(NT) void sparse_topk_kernel(const float* __restrict__ x,
                                                         float* __restrict__ out) {
    const int lane = threadIdx.x;
    const long long wid = blockIdx.x;
    const float* base = x + wid * RPW * D_DIM;
    float* obase = out + wid * RPW * D_DIM;

    // Prefetch buffer: raw float4s of the row being staged.
    float4 nf[8];
    {
        const float4* p = reinterpret_cast<const float4*>(base);
#pragma unroll
        for (int b = 0; b < 8; ++b) nf[b] = p[b * 64 + lane];
    }

#pragma unroll 1
    for (int r = 0; r < RPW; ++r) {
        // Pack staged row into abs-bits + sign word.
        unsigned a[EPL];
        unsigned signs = 0u;
#pragma unroll
        for (int b = 0; b < 8; ++b) {
            const unsigned w0 = __float_as_uint(nf[b].x);
            const unsigned w1 = __float_as_uint(nf[b].y);
            const unsigned w2 = __float_as_uint(nf[b].z);
            const unsigned w3 = __float_as_uint(nf[b].w);
            a[4 * b + 0] = w0 & 0x7fffffffu; signs |= (w0 >> 31) << (4 * b + 0);
            a[4 * b + 1] = w1 & 0x7fffffffu; signs |= (w1 >> 31) << (4 * b + 1);
            a[4 * b + 2] = w2 & 0x7fffffffu; signs |= (w2 >> 31) << (4 * b + 2);
            a[4 * b + 3] = w3 & 0x7fffffffu; signs |= (w3 >> 31) << (4 * b + 3);
        }

        // Issue next row's loads now; they complete during this row's search.
        if (r + 1 < RPW) {
            const float4* pn = reinterpret_cast<const float4*>(base + (r + 1) * D_DIM);
#pragma unroll
            for (int b = 0; b < 8; ++b) nf[b] = pn[b * 64 + lane];
        }

        // Seeded integer bisection on [lo, hi): invariant cnt_ge(lo) >= K,
        // cnt_ge(hi) < K. Early exit when cnt == K (exact top-K set).
        unsigned lo = 0u, hi = 0x7F800000u;
        unsigned thr = 0u;
        bool exact = false;
        int step = 0, lastcnt = 0;
#pragma unroll 1
        while (hi - lo > 1u) {
            unsigned mid;
            if (step == 0)      mid = 0x3FD28F5Cu;                       // ~1.645
            else if (step == 1) mid = (lastcnt > K_SEL) ? 0x3FE66666u    // 1.8
                                                        : 0x3FC00000u;   // 1.5
            else                mid = lo + ((hi - lo) >> 1);
            if (mid <= lo || mid >= hi) mid = lo + ((hi - lo) >> 1);     // guard
            ++step;
            const int cnt = count_ge(a, mid);
            lastcnt = cnt;
            if (cnt == K_SEL) { thr = mid; exact = true; break; }
            if (cnt > K_SEL) lo = mid; else hi = mid;
        }

        finish_row(a, signs, exact, thr, lo, obase + (long long)r * D_DIM, lane);
    }
}

extern "C" void kernel_launch(void* const* d_in, const int* in_sizes, int n_in,
                              void* d_out, int out_size, void* d_ws, size_t ws_size,
                              hipStream_t stream) {
    const float* x = (const float*)d_in[0];
    float* out = (float*)d_out;
    const int rows = in_sizes[0] / D_DIM;               // 16384
    const int blocks = rows / RPW;                      // 8192
    sparse_topk_kernel<<<blocks, NT, 0, stream>>>(x, out);
}